// Round 1
// baseline (2078.265 us; speedup 1.0000x reference)
//
#include <hip/hip_runtime.h>

#define T_STEPS 256
#define FEAT 16
#define U1 24
#define U2 48
#define GROUP 8
#define BLOCK 256
#define GPB (BLOCK / GROUP)  // 32 batch elements per block

// LDS strides (in floats). All rows 16B-aligned (stride*4 % 16 == 0) so the
// compiler can merge weight reads into ds_read_b128. Strides chosen so the 8
// distinct rows read per wave land in <=2-way bank conflicts (2-way is free).
#define ST_W1 20
#define ST_WR1 28
#define ST_W2 28
#define ST_WR2 52

__device__ __forceinline__ float fast_tanh(float z) {
    // tanh(z) = 1 - 2/(1+exp(2z)); robust at +/-inf (exp->0 gives -1, exp->inf gives +1)
    return 1.0f - 2.0f / (1.0f + __expf(2.0f * z));
}

__global__ __launch_bounds__(BLOCK) void rnn_kernel(
    const float* __restrict__ seq,
    const float* __restrict__ W1, const float* __restrict__ b1,
    const float* __restrict__ Wr1, const float* __restrict__ br1,
    const float* __restrict__ g1, const float* __restrict__ be1,
    const float* __restrict__ W2, const float* __restrict__ b2,
    const float* __restrict__ Wr2, const float* __restrict__ br2,
    const float* __restrict__ g2, const float* __restrict__ be2,
    const float* __restrict__ Wout, const float* __restrict__ bout,
    float* __restrict__ out)
{
    __shared__ float sW1T[U1 * ST_W1];
    __shared__ float sWr1T[U1 * ST_WR1];
    __shared__ float sW2T[U2 * ST_W2];
    __shared__ float sWr2T[U2 * ST_WR2];

    const int tid = threadIdx.x;
    // Stage weights into LDS, transposed (row = output unit j, col = input k)
    for (int i = tid; i < FEAT * U1; i += BLOCK) { int k = i / U1, j = i - k * U1; sW1T[j * ST_W1 + k] = W1[i]; }
    for (int i = tid; i < U1 * U1; i += BLOCK) { int k = i / U1, j = i - k * U1; sWr1T[j * ST_WR1 + k] = Wr1[i]; }
    for (int i = tid; i < U1 * U2; i += BLOCK) { int k = i / U2, j = i - k * U2; sW2T[j * ST_W2 + k] = W2[i]; }
    for (int i = tid; i < U2 * U2; i += BLOCK) { int k = i / U2, j = i - k * U2; sWr2T[j * ST_WR2 + k] = Wr2[i]; }
    __syncthreads();

    const int l = tid & (GROUP - 1);   // lane-in-group: owns 3 of U1, 6 of U2
    const int g = tid >> 3;            // group id within block
    const int b = blockIdx.x * GPB + g;
    const int j1 = 3 * l, j2 = 6 * l;

    // Per-lane bias / LN-param registers (loop-invariant)
    float b1r[3], br1r[3], g1r[3], be1r[3];
#pragma unroll
    for (int r = 0; r < 3; ++r) { b1r[r] = b1[j1 + r]; br1r[r] = br1[j1 + r]; g1r[r] = g1[j1 + r]; be1r[r] = be1[j1 + r]; }
    float b2r[6], br2r[6], g2r[6], be2r[6], wor[6];
#pragma unroll
    for (int r = 0; r < 6; ++r) { b2r[r] = b2[j2 + r]; br2r[r] = br2[j2 + r]; g2r[r] = g2[j2 + r]; be2r[r] = be2[j2 + r]; wor[r] = Wout[j2 + r]; }

    // LDS row pointers (loop-invariant)
    const float* w1p0 = &sW1T[(j1 + 0) * ST_W1];
    const float* w1p1 = &sW1T[(j1 + 1) * ST_W1];
    const float* w1p2 = &sW1T[(j1 + 2) * ST_W1];
    const float* wr1p0 = &sWr1T[(j1 + 0) * ST_WR1];
    const float* wr1p1 = &sWr1T[(j1 + 1) * ST_WR1];
    const float* wr1p2 = &sWr1T[(j1 + 2) * ST_WR1];
    const float* w2p[6];
    const float* wr2p[6];
#pragma unroll
    for (int r = 0; r < 6; ++r) { w2p[r] = &sW2T[(j2 + r) * ST_W2]; wr2p[r] = &sWr2T[(j2 + r) * ST_WR2]; }

    const float* base = seq + (size_t)b * (T_STEPS * FEAT);
    // Software-prefetch the first timestep's 16 inputs (each lane holds full input;
    // the 8 lanes of a group hit the same 64B lines -> L1 broadcast, no extra HBM)
    float4 nx0 = ((const float4*)base)[0];
    float4 nx1 = ((const float4*)base)[1];
    float4 nx2 = ((const float4*)base)[2];
    float4 nx3 = ((const float4*)base)[3];

    float s1r0 = 0.f, s1r1 = 0.f, s1r2 = 0.f;
    float s2r[6] = {0.f, 0.f, 0.f, 0.f, 0.f, 0.f};

#pragma unroll 1
    for (int t = 0; t < T_STEPS; ++t) {
        float in[16];
        ((float4*)in)[0] = nx0; ((float4*)in)[1] = nx1;
        ((float4*)in)[2] = nx2; ((float4*)in)[3] = nx3;
        // prefetch next step (clamped so no branch)
        const int tn = (t + 1 < T_STEPS) ? t + 1 : t;
        const float4* spn = (const float4*)(base + tn * FEAT);
        nx0 = spn[0]; nx1 = spn[1]; nx2 = spn[2]; nx3 = spn[3];

        // ---- x = in @ W1 + b1 + s1  (my 3 outputs) ----
        float x0 = b1r[0] + s1r0, x1 = b1r[1] + s1r1, x2 = b1r[2] + s1r2;
#pragma unroll
        for (int k = 0; k < FEAT; ++k) {
            x0 = fmaf(in[k], w1p0[k], x0);
            x1 = fmaf(in[k], w1p1[k], x1);
            x2 = fmaf(in[k], w1p2[k], x2);
        }

        // ---- ns1 = tanh(x_full @ Wr1 + br1); gather x via width-8 shuffles ----
        float a0 = br1r[0], a1 = br1r[1], a2 = br1r[2];
#pragma unroll
        for (int src = 0; src < GROUP; ++src) {
            const float v0 = __shfl(x0, src, GROUP);
            const float v1 = __shfl(x1, src, GROUP);
            const float v2 = __shfl(x2, src, GROUP);
            const int kk = 3 * src;
            a0 = fmaf(v0, wr1p0[kk], a0); a0 = fmaf(v1, wr1p0[kk + 1], a0); a0 = fmaf(v2, wr1p0[kk + 2], a0);
            a1 = fmaf(v0, wr1p1[kk], a1); a1 = fmaf(v1, wr1p1[kk + 1], a1); a1 = fmaf(v2, wr1p1[kk + 2], a1);
            a2 = fmaf(v0, wr1p2[kk], a2); a2 = fmaf(v1, wr1p2[kk + 1], a2); a2 = fmaf(v2, wr1p2[kk + 2], a2);
        }
        const float n0 = fast_tanh(a0), n1 = fast_tanh(a1), n2 = fast_tanh(a2);
        s1r0 = n0; s1r1 = n1; s1r2 = n2;

        // ---- h = LayerNorm(ns1) over 24 units (group butterfly reduce) ----
        float sm = n0 + n1 + n2;
        float sq = n0 * n0 + n1 * n1 + n2 * n2;
        sm += __shfl_xor(sm, 1, GROUP); sq += __shfl_xor(sq, 1, GROUP);
        sm += __shfl_xor(sm, 2, GROUP); sq += __shfl_xor(sq, 2, GROUP);
        sm += __shfl_xor(sm, 4, GROUP); sq += __shfl_xor(sq, 4, GROUP);
        const float mu = sm * (1.0f / U1);
        const float var = sq * (1.0f / U1) - mu * mu;
        const float rs = rsqrtf(var + 1e-3f);
        const float h0 = (n0 - mu) * rs * g1r[0] + be1r[0];
        const float h1 = (n1 - mu) * rs * g1r[1] + be1r[1];
        const float h2 = (n2 - mu) * rs * g1r[2] + be1r[2];

        // ---- y = h_full @ W2 + b2 + s2  (my 6 outputs) ----
        float c0 = b2r[0] + s2r[0], c1 = b2r[1] + s2r[1], c2 = b2r[2] + s2r[2];
        float c3 = b2r[3] + s2r[3], c4 = b2r[4] + s2r[4], c5 = b2r[5] + s2r[5];
#pragma unroll
        for (int src = 0; src < GROUP; ++src) {
            const float v0 = __shfl(h0, src, GROUP);
            const float v1 = __shfl(h1, src, GROUP);
            const float v2 = __shfl(h2, src, GROUP);
            const int kk = 3 * src;
            c0 = fmaf(v0, w2p[0][kk], c0); c0 = fmaf(v1, w2p[0][kk + 1], c0); c0 = fmaf(v2, w2p[0][kk + 2], c0);
            c1 = fmaf(v0, w2p[1][kk], c1); c1 = fmaf(v1, w2p[1][kk + 1], c1); c1 = fmaf(v2, w2p[1][kk + 2], c1);
            c2 = fmaf(v0, w2p[2][kk], c2); c2 = fmaf(v1, w2p[2][kk + 1], c2); c2 = fmaf(v2, w2p[2][kk + 2], c2);
            c3 = fmaf(v0, w2p[3][kk], c3); c3 = fmaf(v1, w2p[3][kk + 1], c3); c3 = fmaf(v2, w2p[3][kk + 2], c3);
            c4 = fmaf(v0, w2p[4][kk], c4); c4 = fmaf(v1, w2p[4][kk + 1], c4); c4 = fmaf(v2, w2p[4][kk + 2], c4);
            c5 = fmaf(v0, w2p[5][kk], c5); c5 = fmaf(v1, w2p[5][kk + 1], c5); c5 = fmaf(v2, w2p[5][kk + 2], c5);
        }

        // ---- ns2 = tanh(y_full @ Wr2 + br2)  (my 6 outputs) ----
        float d0 = br2r[0], d1 = br2r[1], d2 = br2r[2], d3 = br2r[3], d4 = br2r[4], d5 = br2r[5];
#pragma unroll
        for (int src = 0; src < GROUP; ++src) {
            const float u0 = __shfl(c0, src, GROUP);
            const float u1 = __shfl(c1, src, GROUP);
            const float u2 = __shfl(c2, src, GROUP);
            const float u3 = __shfl(c3, src, GROUP);
            const float u4 = __shfl(c4, src, GROUP);
            const float u5 = __shfl(c5, src, GROUP);
            const int kk = 6 * src;
#pragma unroll
            for (int r = 0; r < 6; ++r) {
                float acc = (r == 0) ? d0 : (r == 1) ? d1 : (r == 2) ? d2 : (r == 3) ? d3 : (r == 4) ? d4 : d5;
                const float* w = wr2p[r];
                acc = fmaf(u0, w[kk + 0], acc);
                acc = fmaf(u1, w[kk + 1], acc);
                acc = fmaf(u2, w[kk + 2], acc);
                acc = fmaf(u3, w[kk + 3], acc);
                acc = fmaf(u4, w[kk + 4], acc);
                acc = fmaf(u5, w[kk + 5], acc);
                if (r == 0) d0 = acc; else if (r == 1) d1 = acc; else if (r == 2) d2 = acc;
                else if (r == 3) d3 = acc; else if (r == 4) d4 = acc; else d5 = acc;
            }
        }
        s2r[0] = fast_tanh(d0); s2r[1] = fast_tanh(d1); s2r[2] = fast_tanh(d2);
        s2r[3] = fast_tanh(d3); s2r[4] = fast_tanh(d4); s2r[5] = fast_tanh(d5);
    }

    // ---- epilogue: out = sigmoid(LN(s2, g2, be2) @ Wout + bout) ----
    float sm = 0.f, sq = 0.f;
#pragma unroll
    for (int r = 0; r < 6; ++r) { sm += s2r[r]; sq += s2r[r] * s2r[r]; }
    sm += __shfl_xor(sm, 1, GROUP); sq += __shfl_xor(sq, 1, GROUP);
    sm += __shfl_xor(sm, 2, GROUP); sq += __shfl_xor(sq, 2, GROUP);
    sm += __shfl_xor(sm, 4, GROUP); sq += __shfl_xor(sq, 4, GROUP);
    const float mu = sm * (1.0f / U2);
    const float var = sq * (1.0f / U2) - mu * mu;
    const float rs = rsqrtf(var + 1e-3f);
    float p = 0.f;
#pragma unroll
    for (int r = 0; r < 6; ++r) p += ((s2r[r] - mu) * rs * g2r[r] + be2r[r]) * wor[r];
    p += __shfl_xor(p, 1, GROUP);
    p += __shfl_xor(p, 2, GROUP);
    p += __shfl_xor(p, 4, GROUP);
    if (l == 0) {
        const float z = p + bout[0];
        out[b] = 1.0f / (1.0f + __expf(-z));
    }
}

extern "C" void kernel_launch(void* const* d_in, const int* in_sizes, int n_in,
                              void* d_out, int out_size, void* d_ws, size_t ws_size,
                              hipStream_t stream) {
    const float* seq  = (const float*)d_in[0];
    const float* W1   = (const float*)d_in[1];
    const float* b1   = (const float*)d_in[2];
    const float* Wr1  = (const float*)d_in[3];
    const float* br1  = (const float*)d_in[4];
    const float* g1   = (const float*)d_in[5];
    const float* be1  = (const float*)d_in[6];
    const float* W2   = (const float*)d_in[7];
    const float* b2   = (const float*)d_in[8];
    const float* Wr2  = (const float*)d_in[9];
    const float* br2  = (const float*)d_in[10];
    const float* g2   = (const float*)d_in[11];
    const float* be2  = (const float*)d_in[12];
    const float* Wout = (const float*)d_in[13];
    const float* bout = (const float*)d_in[14];
    float* out = (float*)d_out;

    const int B = in_sizes[0] / (T_STEPS * FEAT);  // 8192
    const int grid = B / GPB;                      // 256 blocks of 256 threads
    rnn_kernel<<<grid, BLOCK, 0, stream>>>(seq, W1, b1, Wr1, br1, g1, be1,
                                           W2, b2, Wr2, br2, g2, be2, Wout, bout, out);
}

// Round 2
// 1219.347 us; speedup vs baseline: 1.7044x; 1.7044x over previous
//
#include <hip/hip_runtime.h>

#define T_STEPS 256
#define FEAT 16
#define U1 24
#define U2 48
#define GROUP 16            // lanes per batch element: 2 teams x 8 subs
#define BLOCK 256
#define GPB (BLOCK / GROUP) // 16 batch elements per block
#define CHUNK 16
#define NCHUNK (T_STEPS / CHUNK)

// LDS strides (floats). Rows 16B-aligned; bank-group patterns checked <=2-way.
#define ST_W1 20
#define ST_WR1 28
#define ST_W2 28
#define ST_WR2 60   // K halves stored at +0 (k<24) and +28 (k>=24)
#define ST_IN 276   // per-element input stride: 16 steps x 16 floats + pad

__device__ __forceinline__ float bperm(int addr, float v) {
    return __int_as_float(__builtin_amdgcn_ds_bpermute(addr, __float_as_int(v)));
}
__device__ __forceinline__ float fast_tanh(float z) {
    // robust at +/-inf: exp->0 gives -1, exp->inf gives +1
    return 1.0f - 2.0f / (1.0f + __expf(2.0f * z));
}

__global__ __launch_bounds__(BLOCK) void rnn_kernel(
    const float* __restrict__ seq,
    const float* __restrict__ W1, const float* __restrict__ b1,
    const float* __restrict__ Wr1, const float* __restrict__ br1,
    const float* __restrict__ g1, const float* __restrict__ be1,
    const float* __restrict__ W2, const float* __restrict__ b2,
    const float* __restrict__ Wr2, const float* __restrict__ br2,
    const float* __restrict__ g2, const float* __restrict__ be2,
    const float* __restrict__ Wout, const float* __restrict__ bout,
    float* __restrict__ out)
{
    __shared__ float sW1T[U1 * ST_W1];
    __shared__ float sWr1T[U1 * ST_WR1];
    __shared__ float sW2T[U2 * ST_W2];
    __shared__ float sWr2T[U2 * ST_WR2];
    __shared__ float sIn[GPB * ST_IN];

    const int tid = threadIdx.x;
    // Stage weights transposed (row = output unit j, col = input k)
    for (int i = tid; i < FEAT * U1; i += BLOCK) { int k = i / U1, j = i - k * U1; sW1T[j * ST_W1 + k] = W1[i]; }
    for (int i = tid; i < U1 * U1; i += BLOCK) { int k = i / U1, j = i - k * U1; sWr1T[j * ST_WR1 + k] = Wr1[i]; }
    for (int i = tid; i < U1 * U2; i += BLOCK) { int k = i / U2, j = i - k * U2; sW2T[j * ST_W2 + k] = W2[i]; }
    for (int i = tid; i < U2 * U2; i += BLOCK) { int k = i / U2, j = i - k * U2; sWr2T[j * ST_WR2 + (k < 24 ? k : k + 4)] = Wr2[i]; }
    __syncthreads();

    const int l16 = tid & 15, team = l16 >> 3, sub = l16 & 7;
    const int ge = tid >> 4;                 // element index within block
    const int b = blockIdx.x * GPB + ge;
    const int j1 = 3 * sub, j2 = 6 * sub;
    const int lane = tid & 63;
    const int grp = lane & ~15;

    // Loop-invariant bpermute byte-addresses
    int ba[4];
#pragma unroll
    for (int j = 0; j < 4; ++j) ba[j] = (grp + team * 4 + j) << 2;
    const int ax1 = (lane ^ 1) << 2, ax2 = (lane ^ 2) << 2;
    const int ax4 = (lane ^ 4) << 2, ax8 = (lane ^ 8) << 2;

    // Input staging lane constants: each wave stores 1KB contiguous per element
    const int seS = tid >> 6;               // base staged-elem, +4 per iter
    const int ttS = (tid & 63) >> 2;        // step within chunk
    const int k4S = tid & 3;                // float4 within step
    const size_t elemBase = (size_t)blockIdx.x * GPB;

    // Per-lane biases / LN params
    float b1r[3], br1r[3], g1r[3], be1r[3];
#pragma unroll
    for (int r = 0; r < 3; ++r) { b1r[r] = b1[j1 + r]; br1r[r] = br1[j1 + r]; g1r[r] = g1[j1 + r]; be1r[r] = be1[j1 + r]; }
    float b2r[6], br2r[6], g2r[6], be2r[6], wor[6];
#pragma unroll
    for (int r = 0; r < 6; ++r) { b2r[r] = b2[j2 + r]; br2r[r] = br2[j2 + r]; g2r[r] = g2[j2 + r]; be2r[r] = be2[j2 + r]; wor[r] = Wout[j2 + r]; }

    // Hoist W1 (this lane's 3 rows x 8 k) into registers — loop-invariant
    float w1f[3][8];
#pragma unroll
    for (int r = 0; r < 3; ++r) {
        float4 q0 = *(const float4*)&sW1T[(j1 + r) * ST_W1 + 8 * team];
        float4 q1 = *(const float4*)&sW1T[(j1 + r) * ST_W1 + 8 * team + 4];
        ((float4*)w1f[r])[0] = q0; ((float4*)w1f[r])[1] = q1;
    }

    const float4* wr1p[3];
#pragma unroll
    for (int r = 0; r < 3; ++r) wr1p[r] = (const float4*)&sWr1T[(j1 + r) * ST_WR1 + 12 * team];
    const float4* w2p[6];
    const float4* wr2p[6];
#pragma unroll
    for (int r = 0; r < 6; ++r) {
        w2p[r] = (const float4*)&sW2T[(j2 + r) * ST_W2 + 12 * team];
        wr2p[r] = (const float4*)&sWr2T[(j2 + r) * ST_WR2 + 28 * team];
    }

    // Prefetch chunk 0
    float4 pre[4];
#pragma unroll
    for (int it = 0; it < 4; ++it)
        pre[it] = *(const float4*)(seq + (elemBase + seS + 4 * it) * (size_t)(T_STEPS * FEAT) + ttS * FEAT + 4 * k4S);

    float s1r0 = 0.f, s1r1 = 0.f, s1r2 = 0.f;
    float s2r[6] = {0.f, 0.f, 0.f, 0.f, 0.f, 0.f};

#pragma unroll 1
    for (int c = 0; c < NCHUNK; ++c) {
        __syncthreads();   // previous chunk's sIn reads complete
#pragma unroll
        for (int it = 0; it < 4; ++it)
            *(float4*)&sIn[(seS + 4 * it) * ST_IN + ttS * 16 + 4 * k4S] = pre[it];
        __syncthreads();
        // prefetch next chunk (clamped)
        const int t0n = (c + 1 < NCHUNK) ? (c + 1) * CHUNK : c * CHUNK;
#pragma unroll
        for (int it = 0; it < 4; ++it)
            pre[it] = *(const float4*)(seq + (elemBase + seS + 4 * it) * (size_t)(T_STEPS * FEAT) + (t0n + ttS) * FEAT + 4 * k4S);

        const float* inbase = &sIn[ge * ST_IN + 8 * team];
#pragma unroll 1
        for (int tt = 0; tt < CHUNK; ++tt) {
            float in8[8];
            ((float4*)in8)[0] = *(const float4*)(inbase + tt * 16);
            ((float4*)in8)[1] = *(const float4*)(inbase + tt * 16 + 4);

            // ---- stage 1: x = in@W1 (+b1+s1 after reduce); my K-half ----
            float x0 = 0.f, x1 = 0.f, x2 = 0.f;
#pragma unroll
            for (int k = 0; k < 8; ++k) {
                x0 = fmaf(in8[k], w1f[0][k], x0);
                x1 = fmaf(in8[k], w1f[1][k], x1);
                x2 = fmaf(in8[k], w1f[2][k], x2);
            }
            float t;
            t = bperm(ax8, x0); x0 = x0 + t + b1r[0] + s1r0;
            t = bperm(ax8, x1); x1 = x1 + t + b1r[1] + s1r1;
            t = bperm(ax8, x2); x2 = x2 + t + b1r[2] + s1r2;

            // ---- stage 2: ns1 = tanh(x@Wr1 + br1); shared-index broadcasts ----
            float v[12];
#pragma unroll
            for (int i = 0; i < 12; ++i) {
                const float srcv = (i % 3 == 0) ? x0 : (i % 3 == 1) ? x1 : x2;
                v[i] = bperm(ba[i / 3], srcv);
            }
            float a[3];
#pragma unroll
            for (int r = 0; r < 3; ++r) {
                const float4 q0 = wr1p[r][0], q1 = wr1p[r][1], q2 = wr1p[r][2];
                float acc = 0.f;
                acc = fmaf(v[0], q0.x, acc); acc = fmaf(v[1], q0.y, acc); acc = fmaf(v[2], q0.z, acc); acc = fmaf(v[3], q0.w, acc);
                acc = fmaf(v[4], q1.x, acc); acc = fmaf(v[5], q1.y, acc); acc = fmaf(v[6], q1.z, acc); acc = fmaf(v[7], q1.w, acc);
                acc = fmaf(v[8], q2.x, acc); acc = fmaf(v[9], q2.y, acc); acc = fmaf(v[10], q2.z, acc); acc = fmaf(v[11], q2.w, acc);
                a[r] = acc;
            }
            t = bperm(ax8, a[0]); const float n0 = fast_tanh(a[0] + t + br1r[0]);
            t = bperm(ax8, a[1]); const float n1 = fast_tanh(a[1] + t + br1r[1]);
            t = bperm(ax8, a[2]); const float n2 = fast_tanh(a[2] + t + br1r[2]);
            s1r0 = n0; s1r1 = n1; s1r2 = n2;

            // ---- stage 3: h = LN(ns1) over 24 (reduce within team) ----
            float sm = n0 + n1 + n2;
            float sq = n0 * n0 + n1 * n1 + n2 * n2;
            t = bperm(ax1, sm); sm += t; t = bperm(ax1, sq); sq += t;
            t = bperm(ax2, sm); sm += t; t = bperm(ax2, sq); sq += t;
            t = bperm(ax4, sm); sm += t; t = bperm(ax4, sq); sq += t;
            const float mu = sm * (1.0f / U1);
            const float var = sq * (1.0f / U1) - mu * mu;
            const float rs = rsqrtf(var + 1e-3f);
            const float h0 = (n0 - mu) * rs * g1r[0] + be1r[0];
            const float h1 = (n1 - mu) * rs * g1r[1] + be1r[1];
            const float h2 = (n2 - mu) * rs * g1r[2] + be1r[2];

            // ---- stage 4: y = h@W2 + b2 + s2 ----
            float hv[12];
#pragma unroll
            for (int i = 0; i < 12; ++i) {
                const float srcv = (i % 3 == 0) ? h0 : (i % 3 == 1) ? h1 : h2;
                hv[i] = bperm(ba[i / 3], srcv);
            }
            float y[6];
#pragma unroll
            for (int r = 0; r < 6; ++r) {
                const float4 q0 = w2p[r][0], q1 = w2p[r][1], q2 = w2p[r][2];
                float acc = 0.f;
                acc = fmaf(hv[0], q0.x, acc); acc = fmaf(hv[1], q0.y, acc); acc = fmaf(hv[2], q0.z, acc); acc = fmaf(hv[3], q0.w, acc);
                acc = fmaf(hv[4], q1.x, acc); acc = fmaf(hv[5], q1.y, acc); acc = fmaf(hv[6], q1.z, acc); acc = fmaf(hv[7], q1.w, acc);
                acc = fmaf(hv[8], q2.x, acc); acc = fmaf(hv[9], q2.y, acc); acc = fmaf(hv[10], q2.z, acc); acc = fmaf(hv[11], q2.w, acc);
                y[r] = acc;
            }
#pragma unroll
            for (int r = 0; r < 6; ++r) { t = bperm(ax8, y[r]); y[r] = y[r] + t + b2r[r] + s2r[r]; }

            // ---- stage 5: ns2 = tanh(y@Wr2 + br2) ----
            float yv[24];
#pragma unroll
            for (int i = 0; i < 24; ++i) yv[i] = bperm(ba[i / 6], y[i % 6]);
#pragma unroll
            for (int r = 0; r < 6; ++r) {
                const float4 q0 = wr2p[r][0], q1 = wr2p[r][1], q2 = wr2p[r][2];
                const float4 q3 = wr2p[r][3], q4 = wr2p[r][4], q5 = wr2p[r][5];
                float acc = 0.f;
                acc = fmaf(yv[0], q0.x, acc); acc = fmaf(yv[1], q0.y, acc); acc = fmaf(yv[2], q0.z, acc); acc = fmaf(yv[3], q0.w, acc);
                acc = fmaf(yv[4], q1.x, acc); acc = fmaf(yv[5], q1.y, acc); acc = fmaf(yv[6], q1.z, acc); acc = fmaf(yv[7], q1.w, acc);
                acc = fmaf(yv[8], q2.x, acc); acc = fmaf(yv[9], q2.y, acc); acc = fmaf(yv[10], q2.z, acc); acc = fmaf(yv[11], q2.w, acc);
                acc = fmaf(yv[12], q3.x, acc); acc = fmaf(yv[13], q3.y, acc); acc = fmaf(yv[14], q3.z, acc); acc = fmaf(yv[15], q3.w, acc);
                acc = fmaf(yv[16], q4.x, acc); acc = fmaf(yv[17], q4.y, acc); acc = fmaf(yv[18], q4.z, acc); acc = fmaf(yv[19], q4.w, acc);
                acc = fmaf(yv[20], q5.x, acc); acc = fmaf(yv[21], q5.y, acc); acc = fmaf(yv[22], q5.z, acc); acc = fmaf(yv[23], q5.w, acc);
                t = bperm(ax8, acc);
                s2r[r] = fast_tanh(acc + t + br2r[r]);
            }
        }
    }

    // ---- epilogue: out = sigmoid(LN(s2) @ Wout + bout) ----
    float sm = 0.f, sq = 0.f, t;
#pragma unroll
    for (int r = 0; r < 6; ++r) { sm += s2r[r]; sq += s2r[r] * s2r[r]; }
    t = bperm(ax1, sm); sm += t; t = bperm(ax1, sq); sq += t;
    t = bperm(ax2, sm); sm += t; t = bperm(ax2, sq); sq += t;
    t = bperm(ax4, sm); sm += t; t = bperm(ax4, sq); sq += t;
    const float mu = sm * (1.0f / U2);
    const float var = sq * (1.0f / U2) - mu * mu;
    const float rs = rsqrtf(var + 1e-3f);
    float p = 0.f;
#pragma unroll
    for (int r = 0; r < 6; ++r) p += ((s2r[r] - mu) * rs * g2r[r] + be2r[r]) * wor[r];
    t = bperm(ax1, p); p += t;
    t = bperm(ax2, p); p += t;
    t = bperm(ax4, p); p += t;
    if (l16 == 0) {
        const float z = p + bout[0];
        out[b] = 1.0f / (1.0f + __expf(-z));
    }
}

extern "C" void kernel_launch(void* const* d_in, const int* in_sizes, int n_in,
                              void* d_out, int out_size, void* d_ws, size_t ws_size,
                              hipStream_t stream) {
    const float* seq  = (const float*)d_in[0];
    const float* W1   = (const float*)d_in[1];
    const float* b1   = (const float*)d_in[2];
    const float* Wr1  = (const float*)d_in[3];
    const float* br1  = (const float*)d_in[4];
    const float* g1   = (const float*)d_in[5];
    const float* be1  = (const float*)d_in[6];
    const float* W2   = (const float*)d_in[7];
    const float* b2   = (const float*)d_in[8];
    const float* Wr2  = (const float*)d_in[9];
    const float* br2  = (const float*)d_in[10];
    const float* g2   = (const float*)d_in[11];
    const float* be2  = (const float*)d_in[12];
    const float* Wout = (const float*)d_in[13];
    const float* bout = (const float*)d_in[14];
    float* out = (float*)d_out;

    const int B = in_sizes[0] / (T_STEPS * FEAT);  // 8192
    const int grid = B / GPB;                      // 512 blocks of 256 threads
    rnn_kernel<<<grid, BLOCK, 0, stream>>>(seq, W1, b1, Wr1, br1, g1, be1,
                                           W2, b2, Wr2, br2, g2, be2, Wout, bout, out);
}

// Round 3
// 515.982 us; speedup vs baseline: 4.0278x; 2.3632x over previous
//
#include <hip/hip_runtime.h>

#define T_STEPS 256
#define FEAT 16
#define U1 24
#define U2 48

typedef short bf16x8 __attribute__((ext_vector_type(8)));
typedef float f32x4 __attribute__((ext_vector_type(4)));

__device__ __forceinline__ unsigned short f2bf(float f) {
    unsigned u = __float_as_uint(f);
    u += 0x7fffu + ((u >> 16) & 1u);   // RNE
    return (unsigned short)(u >> 16);
}
__device__ __forceinline__ unsigned pk2(float a, float b) {
    return (unsigned)f2bf(a) | ((unsigned)f2bf(b) << 16);
}
__device__ __forceinline__ float fast_tanh(float z) {
    return 1.0f - 2.0f / (1.0f + __expf(2.0f * z));
}

union FragU { bf16x8 v; unsigned u[4]; };

#define MFMA(A, B, C) __builtin_amdgcn_mfma_f32_16x16x32_bf16((A), (B), (C), 0, 0, 0)

__global__ __launch_bounds__(64) void rnn_kernel(
    const float* __restrict__ seq,
    const float* __restrict__ W1, const float* __restrict__ b1,
    const float* __restrict__ Wr1, const float* __restrict__ br1,
    const float* __restrict__ g1, const float* __restrict__ be1,
    const float* __restrict__ W2, const float* __restrict__ b2,
    const float* __restrict__ Wr2, const float* __restrict__ br2,
    const float* __restrict__ g2, const float* __restrict__ be2,
    const float* __restrict__ Wout, const float* __restrict__ bout,
    float* __restrict__ out)
{
    // Per-wave transpose scratch: 16 batch rows x 144B (k<=64 bf16 + pad).
    // 144 = 16*9 -> b128 reads hit quad (j15+g)%8: exactly 8 lanes/quad = ideal.
    __shared__ __align__(16) unsigned char tr[16 * 144];

    const int lane = threadIdx.x;        // single wave per block
    const int j15 = lane & 15;
    const int g = lane >> 4;             // k-quad

    // ---- init LDS: zero, then persistent y k=48 slot = 1.0 (folds br2) ----
    for (int i = lane; i < 16 * 144 / 4; i += 64) ((unsigned*)tr)[i] = 0u;
    if (lane < 16) *(unsigned short*)(tr + lane * 144 + 96) = 0x3F80;  // k48 = 1.0bf16

    // ---- build loop-invariant A-frags: A[m=16t+j15][k=8g+j] = W^T (+bias col) ----
    bf16x8 A1[2], A2[2], A3[3], A4[3][2];
#pragma unroll
    for (int t = 0; t < 2; ++t) {
        const int m = 16 * t + j15;
        FragU f1, f2;
#pragma unroll
        for (int j = 0; j < 8; ++j) {
            const int k = 8 * g + j;
            float v1 = 0.f, v2 = 0.f;
            if (m < U1) {
                if (k < FEAT) v1 = W1[k * U1 + m];
                else if (k == FEAT) v1 = b1[m];          // bias col (input k16 == 1)
                if (k < U1) v2 = Wr1[k * U1 + m];
                else if (k == U1) v2 = br1[m];           // bias col (x24 == 1)
            } else if (m == U1 && k == FEAT) {
                v1 = 1.f;                                // makes x24 = 1 each step
            }
            f1.v[j] = (short)f2bf(v1);
            f2.v[j] = (short)f2bf(v2);
        }
        A1[t] = f1.v; A2[t] = f2.v;
    }
#pragma unroll
    for (int t = 0; t < 3; ++t) {
        const int m = 16 * t + j15;                      // < 48 always
        FragU f3, f4a, f4b;
#pragma unroll
        for (int j = 0; j < 8; ++j) {
            const int k = 8 * g + j;                     // 0..31
            float v3 = 0.f;
            if (k < U1) v3 = W2[k * U2 + m];
            else if (k == U1) v3 = b2[m];                // bias col (h24 == 1)
            const int kb = 32 + k;                       // 32..63
            const float va = Wr2[k * U2 + m];
            const float vb = (kb < U2) ? Wr2[kb * U2 + m] : (kb == U2 ? br2[m] : 0.f);
            f3.v[j] = (short)f2bf(v3);
            f4a.v[j] = (short)f2bf(va);
            f4b.v[j] = (short)f2bf(vb);
        }
        A3[t] = f3.v; A4[t][0] = f4a.v; A4[t][1] = f4b.v;
    }

    // ---- LN1 per-lane constants; n==24 slot gets (g=0, be=1) -> h24 = 1 ----
    float g1r[8], be1r[8];
#pragma unroll
    for (int r = 0; r < 8; ++r) {
        const int n = 16 * (r >> 2) + 4 * g + (r & 3);
        g1r[r] = (n < U1) ? g1[n] : 0.f;
        be1r[r] = (n < U1) ? be1[n] : (n == U1 ? 1.f : 0.f);
    }

    const unsigned cdw0 = (g == 2) ? 0x00003F80u : 0u;   // input frag const (k16=1)
    unsigned char* const row = tr + j15 * 144;

    const f32x4 z4 = {0.f, 0.f, 0.f, 0.f};
    f32x4 s1[2] = {z4, z4};
    f32x4 s2[3] = {z4, z4, z4};

    // ---- input prefetch: lanes g<2 load 8 floats (k=8g..8g+7) per step ----
    const float* sp = seq + (size_t)(blockIdx.x * 16 + j15) * (T_STEPS * FEAT) + 8 * g;
    const bool ld = (lane < 32);
    float4 caA, cbA, caB, cbB;
    if (ld) {
        caA = *(const float4*)(sp);      cbA = *(const float4*)(sp + 4);
        caB = *(const float4*)(sp + 16); cbB = *(const float4*)(sp + 20);
    }

    auto step = [&](const float4 ca, const float4 cb) {
        // input B-frag (bf16), with constant tail for g>=2
        FragU inf;
        const unsigned p0 = pk2(ca.x, ca.y), p1 = pk2(ca.z, ca.w);
        const unsigned p2 = pk2(cb.x, cb.y), p3 = pk2(cb.z, cb.w);
        const bool lo = (g < 2);
        inf.u[0] = lo ? p0 : cdw0;
        inf.u[1] = lo ? p1 : 0u;
        inf.u[2] = lo ? p2 : 0u;
        inf.u[3] = lo ? p3 : 0u;

        // GEMM1: x^T = [W1^T|b1] . in^T + s1   (C-layout: batch in lanes)
        f32x4 x0 = MFMA(A1[0], inf.v, s1[0]);
        f32x4 x1 = MFMA(A1[1], inf.v, s1[1]);

        // transpose x -> LDS (bf16 rows [batch][k])
        *(uint2*)(row + 8 * g)      = make_uint2(pk2(x0[0], x0[1]), pk2(x0[2], x0[3]));
        *(uint2*)(row + 32 + 8 * g) = make_uint2(pk2(x1[0], x1[1]), pk2(x1[2], x1[3]));
        const bf16x8 xf = *(const bf16x8*)(row + 16 * g);

        // GEMM2: a = [Wr1^T|br1] . x^T ; ns1 = tanh(a)
        const f32x4 d0 = MFMA(A2[0], xf, z4);
        const f32x4 d1 = MFMA(A2[1], xf, z4);
        float n1a[4], n1b[4];
#pragma unroll
        for (int r = 0; r < 4; ++r) { n1a[r] = fast_tanh(d0[r]); n1b[r] = fast_tanh(d1[r]); }
#pragma unroll
        for (int r = 0; r < 4; ++r) { s1[0][r] = n1a[r]; s1[1][r] = n1b[r]; }

        // LN over 24 (pads are exact zeros)
        float sm = 0.f, sq = 0.f;
#pragma unroll
        for (int r = 0; r < 4; ++r) {
            sm += n1a[r] + n1b[r];
            sq += n1a[r] * n1a[r] + n1b[r] * n1b[r];
        }
        sm += __shfl_xor(sm, 16, 64); sq += __shfl_xor(sq, 16, 64);
        sm += __shfl_xor(sm, 32, 64); sq += __shfl_xor(sq, 32, 64);
        const float mu = sm * (1.f / U1);
        const float var = sq * (1.f / U1) - mu * mu;
        const float rs = rsqrtf(var + 1e-3f);
        float h0[4], h1[4];
#pragma unroll
        for (int r = 0; r < 4; ++r) {
            h0[r] = (n1a[r] - mu) * rs * g1r[r] + be1r[r];
            h1[r] = (n1b[r] - mu) * rs * g1r[4 + r] + be1r[4 + r];   // h24 = 1 via be
        }

        // transpose h -> LDS
        *(uint2*)(row + 8 * g)      = make_uint2(pk2(h0[0], h0[1]), pk2(h0[2], h0[3]));
        *(uint2*)(row + 32 + 8 * g) = make_uint2(pk2(h1[0], h1[1]), pk2(h1[2], h1[3]));
        const bf16x8 hf = *(const bf16x8*)(row + 16 * g);

        // GEMM3: y^T = [W2^T|b2] . h^T + s2
        const f32x4 y0 = MFMA(A3[0], hf, s2[0]);
        const f32x4 y1 = MFMA(A3[1], hf, s2[1]);
        const f32x4 y2 = MFMA(A3[2], hf, s2[2]);

        // transpose y -> LDS (k48 slot = persistent 1.0 -> br2 fold)
        *(uint2*)(row + 8 * g)      = make_uint2(pk2(y0[0], y0[1]), pk2(y0[2], y0[3]));
        *(uint2*)(row + 32 + 8 * g) = make_uint2(pk2(y1[0], y1[1]), pk2(y1[2], y1[3]));
        *(uint2*)(row + 64 + 8 * g) = make_uint2(pk2(y2[0], y2[1]), pk2(y2[2], y2[3]));
        const bf16x8 yf0 = *(const bf16x8*)(row + 16 * g);
        const bf16x8 yf1 = *(const bf16x8*)(row + 64 + 16 * g);

        // GEMM4: e = [Wr2^T|br2] . y^T ; s2 = tanh(e)
#pragma unroll
        for (int t3 = 0; t3 < 3; ++t3) {
            f32x4 e = MFMA(A4[t3][0], yf0, z4);
            e = MFMA(A4[t3][1], yf1, e);
#pragma unroll
            for (int r = 0; r < 4; ++r) s2[t3][r] = fast_tanh(e[r]);
        }
    };

#pragma unroll 1
    for (int t = 0; t < T_STEPS; t += 2) {
        float4 na, nb;
        const int t2 = (t + 2 < T_STEPS) ? t + 2 : t;
        if (ld) { na = *(const float4*)(sp + t2 * 16); nb = *(const float4*)(sp + t2 * 16 + 4); }
        step(caA, cbA);
        caA = na; cbA = nb;
        const int t3c = (t + 3 < T_STEPS) ? t + 3 : t + 1;
        if (ld) { na = *(const float4*)(sp + t3c * 16); nb = *(const float4*)(sp + t3c * 16 + 4); }
        step(caB, cbB);
        caB = na; cbB = nb;
    }

    // ---- epilogue: sigmoid(LN(s2) @ Wout + bout) ----
    float g2r[12], be2r[12], wor[12];
#pragma unroll
    for (int r = 0; r < 12; ++r) {
        const int n = 16 * (r >> 2) + 4 * g + (r & 3);   // < 48
        g2r[r] = g2[n]; be2r[r] = be2[n]; wor[r] = Wout[n];
    }
    float sm = 0.f, sq = 0.f;
#pragma unroll
    for (int tt = 0; tt < 3; ++tt)
#pragma unroll
        for (int r = 0; r < 4; ++r) { const float v = s2[tt][r]; sm += v; sq += v * v; }
    sm += __shfl_xor(sm, 16, 64); sq += __shfl_xor(sq, 16, 64);
    sm += __shfl_xor(sm, 32, 64); sq += __shfl_xor(sq, 32, 64);
    const float mu = sm * (1.f / U2);
    const float var = sq * (1.f / U2) - mu * mu;
    const float rs = rsqrtf(var + 1e-3f);
    float p = 0.f;
#pragma unroll
    for (int tt = 0; tt < 3; ++tt)
#pragma unroll
        for (int r = 0; r < 4; ++r)
            p += ((s2[tt][r] - mu) * rs * g2r[4 * tt + r] + be2r[4 * tt + r]) * wor[4 * tt + r];
    p += __shfl_xor(p, 16, 64);
    p += __shfl_xor(p, 32, 64);
    if (lane < 16) {
        const float z = p + bout[0];
        out[blockIdx.x * 16 + lane] = 1.0f / (1.0f + __expf(-z));
    }
}

extern "C" void kernel_launch(void* const* d_in, const int* in_sizes, int n_in,
                              void* d_out, int out_size, void* d_ws, size_t ws_size,
                              hipStream_t stream) {
    const float* seq  = (const float*)d_in[0];
    const float* W1   = (const float*)d_in[1];
    const float* b1   = (const float*)d_in[2];
    const float* Wr1  = (const float*)d_in[3];
    const float* br1  = (const float*)d_in[4];
    const float* g1   = (const float*)d_in[5];
    const float* be1  = (const float*)d_in[6];
    const float* W2   = (const float*)d_in[7];
    const float* b2   = (const float*)d_in[8];
    const float* Wr2  = (const float*)d_in[9];
    const float* br2  = (const float*)d_in[10];
    const float* g2   = (const float*)d_in[11];
    const float* be2  = (const float*)d_in[12];
    const float* Wout = (const float*)d_in[13];
    const float* bout = (const float*)d_in[14];
    float* out = (float*)d_out;

    const int B = in_sizes[0] / (T_STEPS * FEAT);   // 8192
    const int grid = B / 16;                        // 512 single-wave blocks
    rnn_kernel<<<grid, 64, 0, stream>>>(seq, W1, b1, Wr1, br1, g1, be1,
                                        W2, b2, Wr2, br2, g2, be2, Wout, bout, out);
}

// Round 4
// 469.855 us; speedup vs baseline: 4.4232x; 1.0982x over previous
//
#include <hip/hip_runtime.h>

#define T_STEPS 256
#define FEAT 16
#define U1 24
#define U2 48

typedef short bf16x8 __attribute__((ext_vector_type(8)));
typedef float f32x4 __attribute__((ext_vector_type(4)));

__device__ __forceinline__ unsigned short f2bf(float f) {
    unsigned u = __float_as_uint(f);
    u += 0x7fffu + ((u >> 16) & 1u);   // RNE
    return (unsigned short)(u >> 16);
}
__device__ __forceinline__ unsigned pk2(float a, float b) {
    return (unsigned)f2bf(a) | ((unsigned)f2bf(b) << 16);
}
__device__ __forceinline__ float fast_tanh(float z) {
    return 1.0f - 2.0f / (1.0f + __expf(2.0f * z));
}

union FragU { bf16x8 v; unsigned u[4]; };

#define MFMA(A, B, C) __builtin_amdgcn_mfma_f32_16x16x32_bf16((A), (B), (C), 0, 0, 0)

// lgkm-only barrier: vmcnt(63) expcnt(7) lgkmcnt(0) = 0xC07F — input prefetch
// global loads stay in flight across the barrier (no vmcnt drain).
__device__ __forceinline__ void bar_sync() {
    asm volatile("" ::: "memory");
    __builtin_amdgcn_s_waitcnt(0xC07F);
    __builtin_amdgcn_s_barrier();
    asm volatile("" ::: "memory");
}

#define ROWB 144   // per-row byte stride in all LDS scratch (known conflict behavior)

__global__ __launch_bounds__(128) void rnn_kernel(
    const float* __restrict__ seq,
    const float* __restrict__ W1, const float* __restrict__ b1,
    const float* __restrict__ Wr1, const float* __restrict__ br1,
    const float* __restrict__ g1, const float* __restrict__ be1,
    const float* __restrict__ W2, const float* __restrict__ b2,
    const float* __restrict__ Wr2, const float* __restrict__ br2,
    const float* __restrict__ g2, const float* __restrict__ be2,
    const float* __restrict__ Wout, const float* __restrict__ bout,
    float* __restrict__ out)
{
    __shared__ __align__(16) unsigned char tr0[16 * ROWB];      // producer x-scratch
    __shared__ __align__(16) unsigned char tr1[16 * ROWB];      // consumer y-scratch
    __shared__ __align__(16) unsigned char hbuf[2][16 * ROWB];  // h handoff (double)

    const int tid = threadIdx.x;
    const int w = tid >> 6;              // 0 = layer-1 producer, 1 = layer-2 consumer
    const int lane = tid & 63;
    const int j15 = lane & 15;
    const int g = lane >> 4;
    const f32x4 z4 = {0.f, 0.f, 0.f, 0.f};

    if (w == 0) {
        // ================= PRODUCER: layer 1 =================
        bf16x8 A1[2], A2[2];
#pragma unroll
        for (int t = 0; t < 2; ++t) {
            const int m = 16 * t + j15;
            FragU f1, f2;
#pragma unroll
            for (int j = 0; j < 8; ++j) {
                const int k = 8 * g + j;
                float v1 = 0.f, v2 = 0.f;
                if (m < U1) {
                    if (k < FEAT) v1 = W1[k * U1 + m];
                    else if (k == FEAT) v1 = b1[m];      // bias col (input k16 == 1)
                    if (k < U1) v2 = Wr1[k * U1 + m];
                    else if (k == U1) v2 = br1[m];       // bias col (x24 == 1)
                } else if (m == U1 && k == FEAT) {
                    v1 = 1.f;                            // keeps x24 = 1 each step
                }
                f1.v[j] = (short)f2bf(v1);
                f2.v[j] = (short)f2bf(v2);
            }
            A1[t] = f1.v; A2[t] = f2.v;
        }
        float g1r[8], be1r[8];
#pragma unroll
        for (int r = 0; r < 8; ++r) {
            const int n = 16 * (r >> 2) + 4 * g + (r & 3);
            g1r[r] = (n < U1) ? g1[n] : 0.f;
            be1r[r] = (n < U1) ? be1[n] : (n == U1 ? 1.f : 0.f);  // h24 = 1 via beta
        }
        const unsigned cdw0 = (g == 2) ? 0x00003F80u : 0u;       // input k16 = 1.0
        unsigned char* const xrow = tr0 + j15 * ROWB;

        const float* sp = seq + (size_t)(blockIdx.x * 16 + j15) * (T_STEPS * FEAT) + 8 * g;
        const bool ld = (lane < 32);
        float4 caA, cbA, caB, cbB;
        if (ld) {
            caA = *(const float4*)(sp);      cbA = *(const float4*)(sp + 4);
            caB = *(const float4*)(sp + 16); cbB = *(const float4*)(sp + 20);
        }

        f32x4 s1[2] = {z4, z4};

        auto pstep = [&](int t, const float4 ca, const float4 cb) {
            FragU inf;
            const unsigned p0 = pk2(ca.x, ca.y), p1 = pk2(ca.z, ca.w);
            const unsigned p2 = pk2(cb.x, cb.y), p3 = pk2(cb.z, cb.w);
            const bool lo = (g < 2);
            inf.u[0] = lo ? p0 : cdw0;
            inf.u[1] = lo ? p1 : 0u;
            inf.u[2] = lo ? p2 : 0u;
            inf.u[3] = lo ? p3 : 0u;

            // GEMM1: x^T = [W1^T|b1].in^T + s1
            const f32x4 x0 = MFMA(A1[0], inf.v, s1[0]);
            const f32x4 x1 = MFMA(A1[1], inf.v, s1[1]);

            // transpose x through private scratch
            *(uint2*)(xrow + 8 * g)      = make_uint2(pk2(x0[0], x0[1]), pk2(x0[2], x0[3]));
            *(uint2*)(xrow + 32 + 8 * g) = make_uint2(pk2(x1[0], x1[1]), pk2(x1[2], x1[3]));
            const bf16x8 xf = *(const bf16x8*)(xrow + 16 * g);

            // GEMM2: ns1 = tanh([Wr1^T|br1].x^T)
            const f32x4 d0 = MFMA(A2[0], xf, z4);
            const f32x4 d1 = MFMA(A2[1], xf, z4);
            float n1a[4], n1b[4];
#pragma unroll
            for (int r = 0; r < 4; ++r) { n1a[r] = fast_tanh(d0[r]); n1b[r] = fast_tanh(d1[r]); }
#pragma unroll
            for (int r = 0; r < 4; ++r) { s1[0][r] = n1a[r]; s1[1][r] = n1b[r]; }

            // LN over 24 (pads exact zero)
            float sm = 0.f, sq = 0.f;
#pragma unroll
            for (int r = 0; r < 4; ++r) {
                sm += n1a[r] + n1b[r];
                sq += n1a[r] * n1a[r] + n1b[r] * n1b[r];
            }
            sm += __shfl_xor(sm, 16, 64); sq += __shfl_xor(sq, 16, 64);
            sm += __shfl_xor(sm, 32, 64); sq += __shfl_xor(sq, 32, 64);
            const float mu = sm * (1.f / U1);
            const float var = sq * (1.f / U1) - mu * mu;
            const float rs = rsqrtf(var + 1e-3f);
            float h0[4], h1[4];
#pragma unroll
            for (int r = 0; r < 4; ++r) {
                h0[r] = (n1a[r] - mu) * rs * g1r[r] + be1r[r];
                h1[r] = (n1b[r] - mu) * rs * g1r[4 + r] + be1r[4 + r];
            }
            // handoff: transposed h rows (k0..31, k24 = 1 via beta trick)
            unsigned char* hrow = hbuf[t & 1] + j15 * ROWB;
            *(uint2*)(hrow + 8 * g)      = make_uint2(pk2(h0[0], h0[1]), pk2(h0[2], h0[3]));
            *(uint2*)(hrow + 32 + 8 * g) = make_uint2(pk2(h1[0], h1[1]), pk2(h1[2], h1[3]));
        };

#pragma unroll 1
        for (int t = 0; t < T_STEPS; t += 2) {
            float4 na, nb;
            const int t2 = (t + 2 < T_STEPS) ? t + 2 : t;
            if (ld) { na = *(const float4*)(sp + t2 * 16); nb = *(const float4*)(sp + t2 * 16 + 4); }
            pstep(t, caA, cbA);
            bar_sync();
            caA = na; cbA = nb;
            const int t3 = (t + 3 < T_STEPS) ? t + 3 : t + 1;
            if (ld) { na = *(const float4*)(sp + t3 * 16); nb = *(const float4*)(sp + t3 * 16 + 4); }
            pstep(t + 1, caB, cbB);
            bar_sync();
            caB = na; cbB = nb;
        }
        bar_sync();   // barrier #257
    } else {
        // ================= CONSUMER: layer 2 =================
        // init y-scratch: zeros + persistent k48 = 1.0 (folds br2)
        for (int i = lane; i < 16 * ROWB / 4; i += 64) ((unsigned*)tr1)[i] = 0u;
        if (lane < 16) *(unsigned short*)(tr1 + lane * ROWB + 96) = 0x3F80;

        bf16x8 A3[3], A4[3][2];
#pragma unroll
        for (int t = 0; t < 3; ++t) {
            const int m = 16 * t + j15;
            FragU f3, f4a, f4b;
#pragma unroll
            for (int j = 0; j < 8; ++j) {
                const int k = 8 * g + j;                 // 0..31
                float v3 = 0.f;
                if (k < U1) v3 = W2[k * U2 + m];
                else if (k == U1) v3 = b2[m];            // bias col (h24 == 1)
                const int kb = 32 + k;                   // 32..63
                const float va = Wr2[k * U2 + m];
                const float vb = (kb < U2) ? Wr2[kb * U2 + m] : (kb == U2 ? br2[m] : 0.f);
                f3.v[j] = (short)f2bf(v3);
                f4a.v[j] = (short)f2bf(va);
                f4b.v[j] = (short)f2bf(vb);
            }
            A3[t] = f3.v; A4[t][0] = f4a.v; A4[t][1] = f4b.v;
        }
        unsigned char* const yrow = tr1 + j15 * ROWB;
        f32x4 s2[3] = {z4, z4, z4};

        bar_sync();   // barrier #1 (producer doing step 0)
#pragma unroll 1
        for (int t = 0; t < T_STEPS; ++t) {
            const unsigned char* hrow = hbuf[t & 1] + j15 * ROWB;
            const bf16x8 hf = *(const bf16x8*)(hrow + 16 * g);

            // GEMM3: y^T = [W2^T|b2].h^T + s2
            const f32x4 y0 = MFMA(A3[0], hf, s2[0]);
            const f32x4 y1 = MFMA(A3[1], hf, s2[1]);
            const f32x4 y2 = MFMA(A3[2], hf, s2[2]);

            // transpose y (k48 slot = persistent 1.0)
            *(uint2*)(yrow + 8 * g)      = make_uint2(pk2(y0[0], y0[1]), pk2(y0[2], y0[3]));
            *(uint2*)(yrow + 32 + 8 * g) = make_uint2(pk2(y1[0], y1[1]), pk2(y1[2], y1[3]));
            *(uint2*)(yrow + 64 + 8 * g) = make_uint2(pk2(y2[0], y2[1]), pk2(y2[2], y2[3]));
            const bf16x8 yf0 = *(const bf16x8*)(yrow + 16 * g);
            const bf16x8 yf1 = *(const bf16x8*)(yrow + 64 + 16 * g);

            // GEMM4: s2 = tanh([Wr2^T|br2].y^T)
#pragma unroll
            for (int t3 = 0; t3 < 3; ++t3) {
                f32x4 e = MFMA(A4[t3][0], yf0, z4);
                e = MFMA(A4[t3][1], yf1, e);
#pragma unroll
                for (int r = 0; r < 4; ++r) s2[t3][r] = fast_tanh(e[r]);
            }
            bar_sync();   // barriers #2..#257
        }

        // ---- epilogue: out = sigmoid(LN(s2) @ Wout + bout) ----
        float g2r[12], be2r[12], wor[12];
#pragma unroll
        for (int r = 0; r < 12; ++r) {
            const int n = 16 * (r >> 2) + 4 * g + (r & 3);
            g2r[r] = g2[n]; be2r[r] = be2[n]; wor[r] = Wout[n];
        }
        float sm = 0.f, sq = 0.f;
#pragma unroll
        for (int tt = 0; tt < 3; ++tt)
#pragma unroll
            for (int r = 0; r < 4; ++r) { const float v = s2[tt][r]; sm += v; sq += v * v; }
        sm += __shfl_xor(sm, 16, 64); sq += __shfl_xor(sq, 16, 64);
        sm += __shfl_xor(sm, 32, 64); sq += __shfl_xor(sq, 32, 64);
        const float mu = sm * (1.f / U2);
        const float var = sq * (1.f / U2) - mu * mu;
        const float rs = rsqrtf(var + 1e-3f);
        float p = 0.f;
#pragma unroll
        for (int tt = 0; tt < 3; ++tt)
#pragma unroll
            for (int r = 0; r < 4; ++r)
                p += ((s2[tt][r] - mu) * rs * g2r[4 * tt + r] + be2r[4 * tt + r]) * wor[4 * tt + r];
        p += __shfl_xor(p, 16, 64);
        p += __shfl_xor(p, 32, 64);
        if (lane < 16) {
            const float z = p + bout[0];
            out[blockIdx.x * 16 + lane] = 1.0f / (1.0f + __expf(-z));
        }
    }
}

extern "C" void kernel_launch(void* const* d_in, const int* in_sizes, int n_in,
                              void* d_out, int out_size, void* d_ws, size_t ws_size,
                              hipStream_t stream) {
    const float* seq  = (const float*)d_in[0];
    const float* W1   = (const float*)d_in[1];
    const float* b1   = (const float*)d_in[2];
    const float* Wr1  = (const float*)d_in[3];
    const float* br1  = (const float*)d_in[4];
    const float* g1   = (const float*)d_in[5];
    const float* be1  = (const float*)d_in[6];
    const float* W2   = (const float*)d_in[7];
    const float* b2   = (const float*)d_in[8];
    const float* Wr2  = (const float*)d_in[9];
    const float* br2  = (const float*)d_in[10];
    const float* g2   = (const float*)d_in[11];
    const float* be2  = (const float*)d_in[12];
    const float* Wout = (const float*)d_in[13];
    const float* bout = (const float*)d_in[14];
    float* out = (float*)d_out;

    const int B = in_sizes[0] / (T_STEPS * FEAT);   // 8192
    const int grid = B / 16;                        // 512 blocks x 2 waves
    rnn_kernel<<<grid, 128, 0, stream>>>(seq, W1, b1, Wr1, br1, g1, be1,
                                         W2, b2, Wr2, br2, g2, be2, Wout, bout, out);
}

// Round 5
// 352.629 us; speedup vs baseline: 5.8936x; 1.3324x over previous
//
#include <hip/hip_runtime.h>

#define T_STEPS 256
#define FEAT 16
#define U1 24
#define U2 48
#define ROWB 144      // per-row byte stride (conflict behavior verified R3/R4)
#define SLOTS 8       // ring: 2 macro-steps x 4

typedef short bf16x8 __attribute__((ext_vector_type(8)));
typedef float f32x4 __attribute__((ext_vector_type(4)));

__device__ __forceinline__ unsigned short f2bf(float f) {
    unsigned u = __float_as_uint(f);
    u += 0x7fffu + ((u >> 16) & 1u);   // RNE
    return (unsigned short)(u >> 16);
}

#if defined(__has_builtin)
#if __has_builtin(__builtin_amdgcn_cvt_pk_bf16_f32)
#define HAVE_PKBF16 1
#endif
#endif

__device__ __forceinline__ unsigned pk2(float a, float b) {
#ifdef HAVE_PKBF16
    typedef __bf16 bf2 __attribute__((ext_vector_type(2)));
    union { bf2 v; unsigned u; } cv;
    cv.v = __builtin_amdgcn_cvt_pk_bf16_f32(a, b);   // lo = a, hi = b, RNE
    return cv.u;
#else
    return (unsigned)f2bf(a) | ((unsigned)f2bf(b) << 16);
#endif
}
__device__ __forceinline__ float bfr(float x) {      // round f32 -> bf16 -> f32
    return __uint_as_float(((unsigned)f2bf(x)) << 16);
}
__device__ __forceinline__ float fast_tanh(float z) {
    return 1.0f - 2.0f / (1.0f + __expf(2.0f * z));  // robust at +/-inf
}

union FragU { bf16x8 v; unsigned u[4]; };

#define MFMA(A, B, C) __builtin_amdgcn_mfma_f32_16x16x32_bf16((A), (B), (C), 0, 0, 0)

// lgkm-only barrier (0xC07F = vmcnt(63) expcnt(7) lgkmcnt(0)):
// input-prefetch global loads stay in flight across the barrier.
__device__ __forceinline__ void bar_sync() {
    asm volatile("" ::: "memory");
    __builtin_amdgcn_s_waitcnt(0xC07F);
    __builtin_amdgcn_s_barrier();
    asm volatile("" ::: "memory");
}

__global__ __launch_bounds__(128) void rnn_kernel(
    const float* __restrict__ seq,
    const float* __restrict__ W1, const float* __restrict__ b1,
    const float* __restrict__ Wr1, const float* __restrict__ br1,
    const float* __restrict__ g1, const float* __restrict__ be1,
    const float* __restrict__ W2, const float* __restrict__ b2,
    const float* __restrict__ Wr2, const float* __restrict__ br2,
    const float* __restrict__ g2, const float* __restrict__ be2,
    const float* __restrict__ Wout, const float* __restrict__ bout,
    float* __restrict__ out)
{
    __shared__ __align__(16) unsigned char tr0[16 * ROWB];            // producer x-scratch
    __shared__ __align__(16) unsigned char tr1[16 * ROWB];            // consumer y-scratch
    __shared__ __align__(16) unsigned char ring[SLOTS * 16 * ROWB];   // [n1|n1^2] handoff

    const int tid = threadIdx.x;
    const int w = tid >> 6;              // 0 = layer-1 producer, 1 = layer-2 consumer
    const int lane = tid & 63;
    const int j15 = lane & 15;
    const int g = lane >> 4;
    const f32x4 z4 = {0.f, 0.f, 0.f, 0.f};

    if (w == 0) {
        // ================= PRODUCER: layer 1 (s1 chain) =================
        bf16x8 A1[2], A2[2];
#pragma unroll
        for (int t = 0; t < 2; ++t) {
            const int m = 16 * t + j15;
            FragU f1, f2;
#pragma unroll
            for (int j = 0; j < 8; ++j) {
                const int k = 8 * g + j;
                float v1 = 0.f, v2 = 0.f;
                if (m < U1) {
                    if (k < FEAT) v1 = W1[k * U1 + m];
                    else if (k == FEAT) v1 = b1[m];      // bias col (input k16 == 1)
                    if (k < U1) v2 = Wr1[k * U1 + m];
                    else if (k == U1) v2 = br1[m];       // bias col (x24 == 1)
                } else if (m == U1 && k == FEAT) {
                    v1 = 1.f;                            // keeps x24 = 1 each step
                }
                f1.v[j] = (short)f2bf(v1);
                f2.v[j] = (short)f2bf(v2);
            }
            A1[t] = f1.v; A2[t] = f2.v;
        }
        const unsigned cdw0 = (g == 2) ? 0x00003F80u : 0u;   // input k16 = 1.0
        unsigned char* const xrow = tr0 + j15 * ROWB;

        const float* sp = seq + (size_t)(blockIdx.x * 16 + j15) * (T_STEPS * FEAT) + 8 * g;
        const bool ld = (lane < 32);

        f32x4 s1[2] = {z4, z4};

        auto pstep = [&](int t, const float4 ca, const float4 cb) {
            FragU inf;
            const unsigned p0 = pk2(ca.x, ca.y), p1 = pk2(ca.z, ca.w);
            const unsigned p2 = pk2(cb.x, cb.y), p3 = pk2(cb.z, cb.w);
            const bool lo = (g < 2);
            inf.u[0] = lo ? p0 : cdw0;
            inf.u[1] = lo ? p1 : 0u;
            inf.u[2] = lo ? p2 : 0u;
            inf.u[3] = lo ? p3 : 0u;

            // GEMM1: x^T = [W1^T|b1].in^T + s1
            const f32x4 x0 = MFMA(A1[0], inf.v, s1[0]);
            const f32x4 x1 = MFMA(A1[1], inf.v, s1[1]);

            // transpose x through private scratch
            *(uint2*)(xrow + 8 * g)      = make_uint2(pk2(x0[0], x0[1]), pk2(x0[2], x0[3]));
            *(uint2*)(xrow + 32 + 8 * g) = make_uint2(pk2(x1[0], x1[1]), pk2(x1[2], x1[3]));
            const bf16x8 xf = *(const bf16x8*)(xrow + 16 * g);

            // GEMM2: ns1 = tanh([Wr1^T|br1].x^T)
            const f32x4 d0 = MFMA(A2[0], xf, z4);
            const f32x4 d1 = MFMA(A2[1], xf, z4);
            float n1a[4], n1b[4], qa[4], qb[4];
#pragma unroll
            for (int r = 0; r < 4; ++r) {
                n1a[r] = fast_tanh(d0[r]); n1b[r] = fast_tanh(d1[r]);
                qa[r] = n1a[r] * n1a[r];   qb[r] = n1b[r] * n1b[r];
                s1[0][r] = n1a[r];         s1[1][r] = n1b[r];
            }
            // handoff row: k0..31 = n1 (pads 0), k32..63 = n1^2 (pads 0)
            unsigned char* rp = ring + ((size_t)(t & (SLOTS - 1)) * 16 + j15) * ROWB;
            *(uint2*)(rp + 8 * g)      = make_uint2(pk2(n1a[0], n1a[1]), pk2(n1a[2], n1a[3]));
            *(uint2*)(rp + 32 + 8 * g) = make_uint2(pk2(n1b[0], n1b[1]), pk2(n1b[2], n1b[3]));
            *(uint2*)(rp + 64 + 8 * g) = make_uint2(pk2(qa[0], qa[1]), pk2(qa[2], qa[3]));
            *(uint2*)(rp + 96 + 8 * g) = make_uint2(pk2(qb[0], qb[1]), pk2(qb[2], qb[3]));
        };

        // load macro 0
        float4 ca[4], cb[4], na[4], nb[4];
        if (ld) {
#pragma unroll
            for (int i = 0; i < 4; ++i) {
                ca[i] = *(const float4*)(sp + i * 16);
                cb[i] = *(const float4*)(sp + i * 16 + 4);
            }
        }
#pragma unroll 1
        for (int j = 0; j < 64; ++j) {
            const int jn = (j + 1 < 64) ? j + 1 : j;     // prefetch next macro
            if (ld) {
#pragma unroll
                for (int i = 0; i < 4; ++i) {
                    na[i] = *(const float4*)(sp + (4 * jn + i) * 16);
                    nb[i] = *(const float4*)(sp + (4 * jn + i) * 16 + 4);
                }
            }
#pragma unroll
            for (int i = 0; i < 4; ++i) pstep(4 * j + i, ca[i], cb[i]);
            bar_sync();                                   // 64 in-loop barriers
#pragma unroll
            for (int i = 0; i < 4; ++i) { ca[i] = na[i]; cb[i] = nb[i]; }
        }
        bar_sync();                                       // barrier #65
    } else {
        // ================= CONSUMER: layer 2 (s2 chain) =================
        // y-scratch: zeros + persistent k48 = 1.0 (folds br2 via A4 bias col)
        for (int i = lane; i < 16 * ROWB / 4; i += 64) ((unsigned*)tr1)[i] = 0u;
        if (lane < 16) *(unsigned short*)(tr1 + lane * ROWB + 96) = 0x3F80;

        // A3a[t<3] = gamma-folded W2^T over k(=n1)0..23; A3a[3]/A3b3 = sum rows
        bf16x8 A3a[4], A3b3, A4[3][2];
#pragma unroll
        for (int t = 0; t < 3; ++t) {
            const int m = 16 * t + j15;
            FragU f3, f4a, f4b;
#pragma unroll
            for (int j = 0; j < 8; ++j) {
                const int k = 8 * g + j;                 // 0..31
                const float v3 = (k < U1) ? g1[k] * W2[k * U2 + m] : 0.f;
                const int kb = 32 + k;                   // 32..63
                const float va = Wr2[k * U2 + m];
                const float vb = (kb < U2) ? Wr2[kb * U2 + m] : (kb == U2 ? br2[m] : 0.f);
                f3.v[j] = (short)f2bf(v3);
                f4a.v[j] = (short)f2bf(va);
                f4b.v[j] = (short)f2bf(vb);
            }
            A3a[t] = f3.v; A4[t][0] = f4a.v; A4[t][1] = f4b.v;
        }
        {   // tile3: rows 48+4q -> ones over n1 cols; rows 49+4q -> ones over n1^2 cols
            FragU fa, fb;
#pragma unroll
            for (int j = 0; j < 8; ++j) {
                const int k = 8 * g + j;
                fa.v[j] = ((j15 & 3) == 0 && k < U1) ? (short)0x3F80 : (short)0;
                fb.v[j] = ((j15 & 3) == 1 && k < U1) ? (short)0x3F80 : (short)0;
            }
            A3a[3] = fa.v; A3b3 = fb.v;
        }
        // per-lane LN-fold constants: c[m] = sum_k bf16(g1.W2), d[m] = b2 + W2^T.be1
        float cC[12], dC[12];
#pragma unroll
        for (int i = 0; i < 12; ++i) {
            const int m = 16 * (i >> 2) + 4 * g + (i & 3);
            float cc = 0.f, dd = b2[m];
            for (int k = 0; k < U1; ++k) {
                const float wq = bfr(g1[k] * W2[k * U2 + m]);   // match matmul quantization
                cc += wq;
                dd += be1[k] * W2[k * U2 + m];
            }
            cC[i] = cc; dC[i] = dd;
        }
        unsigned char* const yrow = tr1 + j15 * ROWB;
        f32x4 s2[3] = {z4, z4, z4};

        auto cstep = [&](int t) {
            const unsigned char* rp = ring + ((size_t)(t & (SLOTS - 1)) * 16 + j15) * ROWB;
            const bf16x8 hf0 = *(const bf16x8*)(rp + 16 * g);        // n1, k0..31
            const bf16x8 hf1 = *(const bf16x8*)(rp + 64 + 16 * g);   // n1^2

            // sums first (gates rs), then P tiles
            f32x4 sAcc = MFMA(A3a[3], hf0, z4);
            sAcc = MFMA(A3b3, hf1, sAcc);                 // reg0 = Sum n1, reg1 = Sum n1^2
            const f32x4 P0 = MFMA(A3a[0], hf0, z4);
            const f32x4 P1 = MFMA(A3a[1], hf0, z4);
            const f32x4 P2 = MFMA(A3a[2], hf0, z4);

            const float mu = sAcc[0] * (1.f / U1);
            const float var = sAcc[1] * (1.f / U1) - mu * mu;
            const float rs = rsqrtf(var + 1e-3f);

            // y = rs*(P - mu*c) + (d + s2)
            float y[12];
#pragma unroll
            for (int r = 0; r < 4; ++r) {
                y[r]     = fmaf(rs, fmaf(-mu, cC[r],     P0[r]), dC[r]     + s2[0][r]);
                y[4 + r] = fmaf(rs, fmaf(-mu, cC[4 + r], P1[r]), dC[4 + r] + s2[1][r]);
                y[8 + r] = fmaf(rs, fmaf(-mu, cC[8 + r], P2[r]), dC[8 + r] + s2[2][r]);
            }

            // transpose y (k48 slot = persistent 1.0)
            *(uint2*)(yrow + 8 * g)      = make_uint2(pk2(y[0], y[1]), pk2(y[2], y[3]));
            *(uint2*)(yrow + 32 + 8 * g) = make_uint2(pk2(y[4], y[5]), pk2(y[6], y[7]));
            *(uint2*)(yrow + 64 + 8 * g) = make_uint2(pk2(y[8], y[9]), pk2(y[10], y[11]));
            const bf16x8 yf0 = *(const bf16x8*)(yrow + 16 * g);
            const bf16x8 yf1 = *(const bf16x8*)(yrow + 64 + 16 * g);

            // GEMM4: s2 = tanh([Wr2^T|br2].y^T)
#pragma unroll
            for (int t3 = 0; t3 < 3; ++t3) {
                f32x4 e = MFMA(A4[t3][0], yf0, z4);
                e = MFMA(A4[t3][1], yf1, e);
#pragma unroll
                for (int r = 0; r < 4; ++r) s2[t3][r] = fast_tanh(e[r]);
            }
        };

        bar_sync();                                       // wait for producer macro 0
#pragma unroll 1
        for (int j = 0; j < 64; ++j) {
#pragma unroll
            for (int i = 0; i < 4; ++i) cstep(4 * j + i);
            bar_sync();                                   // 64 in-loop barriers
        }

        // ---- epilogue: out = sigmoid(LN(s2) @ Wout + bout) ----
        float g2r[12], be2r[12], wor[12];
#pragma unroll
        for (int r = 0; r < 12; ++r) {
            const int n = 16 * (r >> 2) + 4 * g + (r & 3);
            g2r[r] = g2[n]; be2r[r] = be2[n]; wor[r] = Wout[n];
        }
        float sm = 0.f, sq = 0.f;
#pragma unroll
        for (int tt = 0; tt < 3; ++tt)
#pragma unroll
            for (int r = 0; r < 4; ++r) { const float v = s2[tt][r]; sm += v; sq += v * v; }
        sm += __shfl_xor(sm, 16, 64); sq += __shfl_xor(sq, 16, 64);
        sm += __shfl_xor(sm, 32, 64); sq += __shfl_xor(sq, 32, 64);
        const float mu = sm * (1.f / U2);
        const float var = sq * (1.f / U2) - mu * mu;
        const float rs = rsqrtf(var + 1e-3f);
        float p = 0.f;
#pragma unroll
        for (int tt = 0; tt < 3; ++tt)
#pragma unroll
            for (int r = 0; r < 4; ++r)
                p += ((s2[tt][r] - mu) * rs * g2r[4 * tt + r] + be2r[4 * tt + r]) * wor[4 * tt + r];
        p += __shfl_xor(p, 16, 64);
        p += __shfl_xor(p, 32, 64);
        if (lane < 16) {
            const float z = p + bout[0];
            out[blockIdx.x * 16 + lane] = 1.0f / (1.0f + __expf(-z));
        }
    }
}

extern "C" void kernel_launch(void* const* d_in, const int* in_sizes, int n_in,
                              void* d_out, int out_size, void* d_ws, size_t ws_size,
                              hipStream_t stream) {
    const float* seq  = (const float*)d_in[0];
    const float* W1   = (const float*)d_in[1];
    const float* b1   = (const float*)d_in[2];
    const float* Wr1  = (const float*)d_in[3];
    const float* br1  = (const float*)d_in[4];
    const float* g1   = (const float*)d_in[5];
    const float* be1  = (const float*)d_in[6];
    const float* W2   = (const float*)d_in[7];
    const float* b2   = (const float*)d_in[8];
    const float* Wr2  = (const float*)d_in[9];
    const float* br2  = (const float*)d_in[10];
    const float* g2   = (const float*)d_in[11];
    const float* be2  = (const float*)d_in[12];
    const float* Wout = (const float*)d_in[13];
    const float* bout = (const float*)d_in[14];
    float* out = (float*)d_out;

    const int B = in_sizes[0] / (T_STEPS * FEAT);   // 8192
    const int grid = B / 16;                        // 512 blocks x 2 waves
    rnn_kernel<<<grid, 128, 0, stream>>>(seq, W1, b1, Wr1, br1, g1, be1,
                                         W2, b2, Wr2, br2, g2, be2, Wout, bout, out);
}